// Round 3
// baseline (247.343 us; speedup 1.0000x reference)
//
#include <hip/hip_runtime.h>

// DIAGNOSTIC ROUND: pure-VALU sliding-window block-causal flash attention.
// No MFMA, no layout assumptions — bisects "flash/mask logic" vs "MFMA usage".
// B=2 H=8 S=4096 D=64, BLK=32, W=16. f32 I/O, f32 compute.
// One WG (256 thr) per (b,h,qblock). Thread t -> (q = t>>3, dchunk c = t&7).

#define NH    8
#define SEQ   4096
#define DIM   64
#define NBLK  128
#define WIN   16

typedef float f32x4 __attribute__((ext_vector_type(4)));

#define TSTR 68   // tile row stride (f32): 64 + 4 pad
#define SSTR 36   // score row stride: 32 + 4 pad

__global__ __launch_bounds__(256)
void sparse_attn_valu(const float* __restrict__ Q,
                      const float* __restrict__ K,
                      const float* __restrict__ V,
                      float* __restrict__ O)
{
    const int wg = blockIdx.x;
    const int n  = wg & (NBLK - 1);
    const int bh = wg >> 7;
    const int t  = (int)threadIdx.x;
    const int q  = t >> 3;        // query row within block: 0..31
    const int c  = t & 7;         // d-chunk / key-subset: 0..7

    __shared__ float Qb[32][TSTR];
    __shared__ float Kb[32][TSTR];
    __shared__ float Vb[32][TSTR];
    __shared__ float Sb[32][SSTR];

    const size_t base = (size_t)bh * SEQ * DIM;

    // stage Q tile once (each thread: 8 contiguous floats of one row)
    {
        const float* qp = Q + base + (size_t)(n * 32 + q) * DIM + c * 8;
        *(f32x4*)&Qb[q][c * 8]     = *(const f32x4*)qp;
        *(f32x4*)&Qb[q][c * 8 + 4] = *(const f32x4*)(qp + 4);
    }

    float acc[8] = {};
    float mrow = -1e30f, lrow = 0.f;
    const float SC = 0.125f * 1.44269504088896340736f;  // d^-0.5 * log2(e)

    const int w0 = (n >= WIN - 1) ? 0 : (WIN - 1 - n);
    for (int w = w0; w < WIN; ++w) {
        const int kb = n - (WIN - 1) + w;

        __syncthreads();   // barrier A: prev iter done reading Kb/Vb/Sb

        // stage K,V tiles for this key-block
        {
            const float* kp = K + base + (size_t)(kb * 32 + q) * DIM + c * 8;
            const float* vp = V + base + (size_t)(kb * 32 + q) * DIM + c * 8;
            *(f32x4*)&Kb[q][c * 8]     = *(const f32x4*)kp;
            *(f32x4*)&Kb[q][c * 8 + 4] = *(const f32x4*)(kp + 4);
            *(f32x4*)&Vb[q][c * 8]     = *(const f32x4*)vp;
            *(f32x4*)&Vb[q][c * 8 + 4] = *(const f32x4*)(vp + 4);
        }

        __syncthreads();   // barrier B: tiles staged

        // QK^T: thread (q,c) computes full dots for keys c, c+8, c+16, c+24
        for (int ki = 0; ki < 4; ++ki) {
            const int k = c + ki * 8;
            float s = 0.f;
            for (int d4 = 0; d4 < 16; ++d4) {
                f32x4 qv = *(const f32x4*)&Qb[q][d4 * 4];
                f32x4 kv = *(const f32x4*)&Kb[k][d4 * 4];
                s += qv[0] * kv[0] + qv[1] * kv[1]
                   + qv[2] * kv[2] + qv[3] * kv[3];
            }
            s *= SC;                                   // exp2 domain
            if (w == WIN - 1 && k > q) s = -1e30f;     // causal mask, diagonal only
            Sb[q][k] = s;
        }

        __syncthreads();   // barrier C: scores ready

        // online softmax + PV (8 threads per row redundantly compute row stats)
        float rmax = -1e30f;
        for (int k = 0; k < 32; ++k) rmax = fmaxf(rmax, Sb[q][k]);
        const float mn    = fmaxf(mrow, rmax);
        const float alpha = exp2f(mrow - mn);          // first block: ~0
#pragma unroll
        for (int j = 0; j < 8; ++j) acc[j] *= alpha;

        float ps = 0.f;
        for (int k = 0; k < 32; ++k) {
            const float p = exp2f(Sb[q][k] - mn);      // masked: exp2(-1e30) = 0
            ps += p;
            f32x4 v0 = *(const f32x4*)&Vb[k][c * 8];
            f32x4 v1 = *(const f32x4*)&Vb[k][c * 8 + 4];
            acc[0] += p * v0[0]; acc[1] += p * v0[1];
            acc[2] += p * v0[2]; acc[3] += p * v0[3];
            acc[4] += p * v1[0]; acc[5] += p * v1[1];
            acc[6] += p * v1[2]; acc[7] += p * v1[3];
        }
        mrow = mn;
        lrow = lrow * alpha + ps;
    }

    // epilogue: normalize, store f32 (each element written exactly once)
    const float inv = 1.0f / lrow;
    float* op = O + base + (size_t)(n * 32 + q) * DIM + c * 8;
#pragma unroll
    for (int j = 0; j < 8; ++j) op[j] = acc[j] * inv;
}

extern "C" void kernel_launch(void* const* d_in, const int* in_sizes, int n_in,
                              void* d_out, int out_size, void* d_ws, size_t ws_size,
                              hipStream_t stream)
{
    const float* Q = (const float*)d_in[0];
    const float* K = (const float*)d_in[1];
    const float* V = (const float*)d_in[2];
    float*       O = (float*)d_out;

    const int nwg = 2 * NH * NBLK;   // 2048 = (b*h) x qblock
    hipLaunchKernelGGL(sparse_attn_valu, dim3(nwg), dim3(256), 0, stream,
                       Q, K, V, O);
}

// Round 4
// 140.265 us; speedup vs baseline: 1.7634x; 1.7634x over previous
//
#include <hip/hip_runtime.h>
#include <hip/hip_bf16.h>

// BISECTION ROUND: MFMA QK^T + (proven) VALU softmax/PV.
// Sliding-window block-causal attention. B=2 H=8 S=4096 D=64, BLK=32, W=16.
// f32 I/O; QK^T in bf16 MFMA (16x16x32), scores -> LDS, rest identical to
// the round-3 passing VALU kernel.

#define NH    8
#define SEQ   4096
#define DIM   64
#define NBLK  128
#define WIN   16

typedef __bf16 bf16x8 __attribute__((ext_vector_type(8)));
typedef float  f32x4  __attribute__((ext_vector_type(4)));

#define TSTR 68   // V tile row stride (f32): 64 + 4 pad
#define SSTR 36   // score row stride: 32 + 4 pad

__device__ __forceinline__ bf16x8 load_cvt8(const float* __restrict__ p) {
    f32x4 a = *reinterpret_cast<const f32x4*>(p);
    f32x4 b = *reinterpret_cast<const f32x4*>(p + 4);
    bf16x8 r;
#pragma unroll
    for (int j = 0; j < 4; ++j) { r[j] = (__bf16)a[j]; r[4 + j] = (__bf16)b[j]; }
    return r;
}

__global__ __launch_bounds__(256)
void sparse_attn_mqk(const float* __restrict__ Q,
                     const float* __restrict__ K,
                     const float* __restrict__ V,
                     float* __restrict__ O)
{
    const int wg   = blockIdx.x;
    const int n    = wg & (NBLK - 1);
    const int bh   = wg >> 7;
    const int t    = (int)threadIdx.x;
    const int wave = t >> 6;          // 0..3
    const int lane = t & 63;
    const int l15  = lane & 15;
    const int l4   = lane >> 4;       // 0..3
    const int qhalf = wave >> 1;      // score tile: query half
    const int khalf = wave & 1;       //             key half

    __shared__ float Vb[32][TSTR];
    __shared__ float Sb[32][SSTR];

    const size_t base = (size_t)bh * SEQ * DIM;
    const float SC = 0.125f * 1.44269504088896340736f;  // d^-0.5 * log2(e)

    // ---- per-wave Q fragments (A operand): row = qhalf*16 + (lane&15),
    //      k-slot j of chunk c = d = c*32 + (lane>>4)*8 + j
    bf16x8 qf[2];
    {
        const float* qp = Q + base + (size_t)(n * 32 + qhalf * 16 + l15) * DIM + l4 * 8;
        qf[0] = load_cvt8(qp);
        qf[1] = load_cvt8(qp + 32);
    }

    // ---- PV thread mapping (identical to passing VALU kernel) ----
    const int q = t >> 3;   // 0..31
    const int c = t & 7;    // 0..7

    float acc[8] = {};
    float mrow = -1e30f, lrow = 0.f;

    const int w0 = (n >= WIN - 1) ? 0 : (WIN - 1 - n);
    for (int w = w0; w < WIN; ++w) {
        const int kb = n - (WIN - 1) + w;

        __syncthreads();   // A: prev iter done reading Vb/Sb

        // ---- stage V tile (f32, unchanged from passing kernel) ----
        {
            const float* vp = V + base + (size_t)(kb * 32 + q) * DIM + c * 8;
            *(f32x4*)&Vb[q][c * 8]     = *(const f32x4*)vp;
            *(f32x4*)&Vb[q][c * 8 + 4] = *(const f32x4*)(vp + 4);
        }

        // ---- MFMA QK^T: each wave computes 16x16 tile (qhalf, khalf) ----
        {
            const float* kp = K + base + (size_t)(kb * 32 + khalf * 16 + l15) * DIM + l4 * 8;
            bf16x8 k0 = load_cvt8(kp);        // B operand: col = lane&15 (key)
            bf16x8 k1 = load_cvt8(kp + 32);
            f32x4 a = {};
            a = __builtin_amdgcn_mfma_f32_16x16x32_bf16(qf[0], k0, a, 0, 0, 0);
            a = __builtin_amdgcn_mfma_f32_16x16x32_bf16(qf[1], k1, a, 0, 0, 0);

            // C/D map under test: col(key) = lane&15, row(query) = (lane>>4)*4 + r
#pragma unroll
            for (int r = 0; r < 4; ++r) {
                const int kw = khalf * 16 + l15;
                const int qw = qhalf * 16 + l4 * 4 + r;
                float sv = a[r] * SC;
                if (w == WIN - 1 && kw > qw) sv = -1e30f;
                Sb[qw][kw] = sv;
            }
        }

        __syncthreads();   // B: Vb staged + Sb written

        // ---- online softmax + PV (byte-for-byte from passing kernel) ----
        float rmax = -1e30f;
        for (int k = 0; k < 32; ++k) rmax = fmaxf(rmax, Sb[q][k]);
        const float mn    = fmaxf(mrow, rmax);
        const float alpha = exp2f(mrow - mn);
#pragma unroll
        for (int j = 0; j < 8; ++j) acc[j] *= alpha;

        float ps = 0.f;
        for (int k = 0; k < 32; ++k) {
            const float p = exp2f(Sb[q][k] - mn);
            ps += p;
            f32x4 v0 = *(const f32x4*)&Vb[k][c * 8];
            f32x4 v1 = *(const f32x4*)&Vb[k][c * 8 + 4];
            acc[0] += p * v0[0]; acc[1] += p * v0[1];
            acc[2] += p * v0[2]; acc[3] += p * v0[3];
            acc[4] += p * v1[0]; acc[5] += p * v1[1];
            acc[6] += p * v1[2]; acc[7] += p * v1[3];
        }
        mrow = mn;
        lrow = lrow * alpha + ps;
    }

    // ---- epilogue ----
    const float inv = 1.0f / lrow;
    float* op = O + base + (size_t)(n * 32 + q) * DIM + c * 8;
#pragma unroll
    for (int j = 0; j < 8; ++j) op[j] = acc[j] * inv;
}

extern "C" void kernel_launch(void* const* d_in, const int* in_sizes, int n_in,
                              void* d_out, int out_size, void* d_ws, size_t ws_size,
                              hipStream_t stream)
{
    const float* Q = (const float*)d_in[0];
    const float* K = (const float*)d_in[1];
    const float* V = (const float*)d_in[2];
    float*       O = (float*)d_out;

    const int nwg = 2 * NH * NBLK;   // 2048 = (b*h) x qblock
    hipLaunchKernelGGL(sparse_attn_mqk, dim3(nwg), dim3(256), 0, stream,
                       Q, K, V, O);
}

// Round 5
// 109.067 us; speedup vs baseline: 2.2678x; 1.2860x over previous
//
#include <hip/hip_runtime.h>
#include <hip/hip_bf16.h>

// Full-MFMA sliding-window block-causal attention (incremental from verified r4).
// B=2 H=8 S=4096 D=64, BLK=32, W=16. f32 I/O, bf16 MFMA QK^T + PV, f32 softmax.
// One WG (256 thr = 4 waves) per (b,h,qblock).
// QK^T tiles: wave=(qhalf,khalf). PV tiles: wave=(qhalf,dhalf), 2 d-tiles each.

#define NH    8
#define SEQ   4096
#define DIM   64
#define NBLK  128
#define WIN   16

typedef __bf16 bf16x8 __attribute__((ext_vector_type(8)));
typedef float  f32x4  __attribute__((ext_vector_type(4)));

#define SSTR 36   // Sb row stride (f32)
#define PSTR 40   // Pb row stride (bf16)
#define VSTR 40   // Vt row stride (bf16)

__device__ __forceinline__ bf16x8 load_cvt8(const float* __restrict__ p) {
    f32x4 a = *reinterpret_cast<const f32x4*>(p);
    f32x4 b = *reinterpret_cast<const f32x4*>(p + 4);
    bf16x8 r;
#pragma unroll
    for (int j = 0; j < 4; ++j) { r[j] = (__bf16)a[j]; r[4 + j] = (__bf16)b[j]; }
    return r;
}

__global__ __launch_bounds__(256)
void sparse_attn_mfma(const float* __restrict__ Q,
                      const float* __restrict__ K,
                      const float* __restrict__ V,
                      float* __restrict__ O)
{
    const int wg   = blockIdx.x;
    const int n    = wg & (NBLK - 1);
    const int bh   = wg >> 7;
    const int t    = (int)threadIdx.x;
    const int wave = t >> 6;
    const int lane = t & 63;
    const int l15  = lane & 15;
    const int l4   = lane >> 4;       // 0..3
    const int qhalf = wave >> 1;      // QK^T: query half; PV: query half
    const int khalf = wave & 1;       // QK^T: key half;   PV: d half

    __shared__ float          Sb[32][SSTR];        // scores (f32)
    __shared__ unsigned short Pb[32][PSTR];        // P bf16: [q][key]
    __shared__ unsigned short Vt[DIM][VSTR];       // V^T bf16: [d][key]
    __shared__ float          mrow_s[32], lrow_s[32], alpha_s[32];

    const size_t base = (size_t)bh * SEQ * DIM;
    const float SC = 0.125f * 1.44269504088896340736f;  // d^-0.5 * log2(e)

    // ---- Q fragments (verified r4): row = qhalf*16 + l15, k-slot = l4*8+j ----
    bf16x8 qf[2];
    {
        const float* qp = Q + base + (size_t)(n * 32 + qhalf * 16 + l15) * DIM + l4 * 8;
        qf[0] = load_cvt8(qp);
        qf[1] = load_cvt8(qp + 32);
    }

    // softmax thread mapping (proven r3/r4): row q = t>>3, sub c = t&7 (same wave per row)
    const int q = t >> 3;
    const int c = t & 7;

    if (t < 32) { mrow_s[t] = -1e30f; lrow_s[t] = 0.f; }

    f32x4 acc[2] = {};   // PV accumulator: tiles d = khalf*32 + dt*16

    const int w0 = (n >= WIN - 1) ? 0 : (WIN - 1 - n);
    for (int w = w0; w < WIN; ++w) {
        const int kb = n - (WIN - 1) + w;

        __syncthreads();   // A: prev softmax done with Sb, prev PV done with Pb/Vt

        // ---- stage V^T (f32 -> bf16): thread (key=t&31, dgroup=t>>5) ----
        {
            const int key = t & 31;
            const int dg  = t >> 5;           // 0..7 -> d = dg*8 .. dg*8+7
            const float* vp = V + base + (size_t)(kb * 32 + key) * DIM + dg * 8;
            f32x4 v0 = *(const f32x4*)vp;
            f32x4 v1 = *(const f32x4*)(vp + 4);
#pragma unroll
            for (int j = 0; j < 4; ++j) {
                Vt[dg * 8 + j][key]     = __builtin_bit_cast(unsigned short, (__bf16)v0[j]);
                Vt[dg * 8 + 4 + j][key] = __builtin_bit_cast(unsigned short, (__bf16)v1[j]);
            }
        }

        // ---- MFMA QK^T (verified r4): wave tile (qhalf, khalf) ----
        {
            const float* kp = K + base + (size_t)(kb * 32 + khalf * 16 + l15) * DIM + l4 * 8;
            bf16x8 k0 = load_cvt8(kp);
            bf16x8 k1 = load_cvt8(kp + 32);
            f32x4 a = {};
            a = __builtin_amdgcn_mfma_f32_16x16x32_bf16(qf[0], k0, a, 0, 0, 0);
            a = __builtin_amdgcn_mfma_f32_16x16x32_bf16(qf[1], k1, a, 0, 0, 0);
#pragma unroll
            for (int r = 0; r < 4; ++r) {
                const int kw = khalf * 16 + l15;
                const int qw = qhalf * 16 + l4 * 4 + r;
                float sv = a[r] * SC;
                if (w == WIN - 1 && kw > qw) sv = -1e30f;
                Sb[qw][kw] = sv;
            }
        }

        __syncthreads();   // B: Sb + Vt ready

        // ---- softmax (proven structure): update m/l, write P bf16 + alpha ----
        {
            float rmax = -1e30f;
            for (int k = 0; k < 32; ++k) rmax = fmaxf(rmax, Sb[q][k]);
            const float mold  = mrow_s[q];            // all 8 row-threads same wave
            const float mn    = fmaxf(mold, rmax);
            const float alpha = exp2f(mold - mn);
            float ps = 0.f;
#pragma unroll
            for (int i = 0; i < 4; ++i) {
                const int k = c * 4 + i;
                const float p = exp2f(Sb[q][k] - mn);
                ps += p;
                Pb[q][k] = __builtin_bit_cast(unsigned short, (__bf16)p);
            }
            // sum ps across the 8 threads of this row (contiguous lanes)
            ps += __shfl_xor(ps, 1);
            ps += __shfl_xor(ps, 2);
            ps += __shfl_xor(ps, 4);
            if (c == 0) {
                mrow_s[q]  = mn;
                alpha_s[q] = alpha;
                lrow_s[q]  = lrow_s[q] * alpha + ps;
            }
        }

        __syncthreads();   // C: Pb + alpha ready

        // ---- MFMA PV: wave tile rows qhalf*16.., cols (khalf as dhalf)*32.. ----
        {
            bf16x8 pf = *reinterpret_cast<const bf16x8*>(&Pb[qhalf * 16 + l15][l4 * 8]);
            float al[4];
#pragma unroll
            for (int r = 0; r < 4; ++r) al[r] = alpha_s[qhalf * 16 + l4 * 4 + r];
#pragma unroll
            for (int dt = 0; dt < 2; ++dt) {
                bf16x8 vf = *reinterpret_cast<const bf16x8*>(
                    &Vt[khalf * 32 + dt * 16 + l15][l4 * 8]);
#pragma unroll
                for (int r = 0; r < 4; ++r) acc[dt][r] *= al[r];
                acc[dt] = __builtin_amdgcn_mfma_f32_16x16x32_bf16(pf, vf, acc[dt], 0, 0, 0);
            }
        }
    }

    // ---- epilogue: normalize rows, store f32 (each element once) ----
#pragma unroll
    for (int r = 0; r < 4; ++r) {
        const int qw = qhalf * 16 + l4 * 4 + r;
        const float inv = 1.0f / lrow_s[qw];
        float* op = O + base + (size_t)(n * 32 + qw) * DIM + khalf * 32 + l15;
        op[0]  = acc[0][r] * inv;
        op[16] = acc[1][r] * inv;
    }
}

extern "C" void kernel_launch(void* const* d_in, const int* in_sizes, int n_in,
                              void* d_out, int out_size, void* d_ws, size_t ws_size,
                              hipStream_t stream)
{
    const float* Q = (const float*)d_in[0];
    const float* K = (const float*)d_in[1];
    const float* V = (const float*)d_in[2];
    float*       O = (float*)d_out;

    const int nwg = 2 * NH * NBLK;   // 2048 = (b*h) x qblock
    hipLaunchKernelGGL(sparse_attn_mfma, dim3(nwg), dim3(256), 0, stream,
                       Q, K, V, O);
}

// Round 6
// 78.828 us; speedup vs baseline: 3.1378x; 1.3836x over previous
//
#include <hip/hip_runtime.h>
#include <hip/hip_bf16.h>

// Sliding-window block-causal attention, grouped q-blocks. MI355X gfx950.
// B=2 H=8 S=4096 D=64, BLK=32, W=16. f32 I/O, bf16 MFMA, f32 softmax.
// WG = 512 thr (8 waves) handles QG=4 consecutive q-blocks (128 rows).
// Iterates the UNION window (19 key blocks); each wave participates in its
// own 16-block sub-window. K/V logical traffic /3.4 vs per-q-block WGs.

#define NH    8
#define SEQ   4096
#define DIM   64
#define NBLK  128
#define WIN   16
#define QG    4
#define GROUPS (NBLK / QG)   // 32

typedef __bf16 bf16x8 __attribute__((ext_vector_type(8)));
typedef float  f32x4  __attribute__((ext_vector_type(4)));

#define SSTR 36   // Sb row stride (f32)
#define PSTR 40   // Pb row stride (bf16)
#define VSTR 40   // Vt row stride (bf16)

__device__ __forceinline__ bf16x8 load_cvt8(const float* __restrict__ p) {
    f32x4 a = *reinterpret_cast<const f32x4*>(p);
    f32x4 b = *reinterpret_cast<const f32x4*>(p + 4);
    bf16x8 r;
#pragma unroll
    for (int j = 0; j < 4; ++j) { r[j] = (__bf16)a[j]; r[4 + j] = (__bf16)b[j]; }
    return r;
}

__global__ __launch_bounds__(512)
void sparse_attn_grp(const float* __restrict__ Q,
                     const float* __restrict__ K,
                     const float* __restrict__ V,
                     float* __restrict__ O)
{
    // XCD-chunked swizzle: 512 WGs, XCD x gets logical ids [x*64, x*64+64)
    const int b  = (int)blockIdx.x;
    const int lg = (b & 7) * 64 + (b >> 3);
    const int bh  = lg >> 5;          // 0..15
    const int grp = lg & 31;
    const int n0  = grp * QG;         // first q-block of group

    const int t    = (int)threadIdx.x;
    const int wave = t >> 6;          // 0..7
    const int lane = t & 63;
    const int l15  = lane & 15;
    const int l4   = lane >> 4;       // 0..3
    const int nq   = n0 + (wave >> 1);      // this wave's q-block
    const int qtrow = wave * 16;            // tile row base within group

    __shared__ float          Sb[128][SSTR];
    __shared__ unsigned short Pb[128][PSTR];
    __shared__ unsigned short Vt[DIM][VSTR];
    __shared__ float          mrow_s[128], lrow_s[128], alpha_s[128];

    const size_t base = (size_t)bh * SEQ * DIM;
    const float SC = 0.125f * 1.44269504088896340736f;  // d^-0.5 * log2(e)

    // ---- Q fragments (verified): A row = qtrow + l15, k-slot = l4*8 + j ----
    bf16x8 qf[2];
    {
        const float* qp = Q + base + (size_t)(n0 * 32 + qtrow + l15) * DIM + l4 * 8;
        qf[0] = load_cvt8(qp);
        qf[1] = load_cvt8(qp + 32);
    }

    // softmax mapping: row q = t>>2 (0..127), sub c = t&3 (8 keys each)
    const int q = t >> 2;
    const int c = t & 3;

    if (t < 128) { mrow_s[t] = -1e30f; lrow_s[t] = 0.f; }

    f32x4 acc[4] = {};   // 4 d-tiles of 16 cols for this wave's 16 rows

    const int kb0 = (n0 >= WIN - 1) ? (n0 - (WIN - 1)) : 0;
    const int kb1 = n0 + QG - 1;
    const int qrowblk = n0 + (q >> 5);  // softmax row's q-block

    for (int kb = kb0; kb <= kb1; ++kb) {
        const bool part  = (kb <= nq) && (kb >= nq - (WIN - 1));      // wave-uniform
        const bool spart = (kb <= qrowblk) && (kb >= qrowblk - (WIN - 1));

        __syncthreads();   // A: prev softmax done w/ Sb, prev PV done w/ Pb/Vt

        // ---- stage V^T (f32->bf16): t -> (key = t&31, dg = t>>5, 4 d's) ----
        {
            const int key = t & 31;
            const int dg  = t >> 5;           // 0..15
            const float* vp = V + base + (size_t)(kb * 32 + key) * DIM + dg * 4;
            f32x4 v0 = *(const f32x4*)vp;
#pragma unroll
            for (int j = 0; j < 4; ++j)
                Vt[dg * 4 + j][key] = __builtin_bit_cast(unsigned short, (__bf16)v0[j]);
        }

        // ---- MFMA QK^T (verified r4): 16 rows x 32 keys per wave ----
        if (part) {
            const float* kp = K + base + (size_t)(kb * 32 + l15) * DIM + l4 * 8;
#pragma unroll
            for (int kh = 0; kh < 2; ++kh) {
                bf16x8 k0 = load_cvt8(kp + kh * 16 * DIM);
                bf16x8 k1 = load_cvt8(kp + kh * 16 * DIM + 32);
                f32x4 a = {};
                a = __builtin_amdgcn_mfma_f32_16x16x32_bf16(qf[0], k0, a, 0, 0, 0);
                a = __builtin_amdgcn_mfma_f32_16x16x32_bf16(qf[1], k1, a, 0, 0, 0);
#pragma unroll
                for (int r = 0; r < 4; ++r) {
                    const int kw = kh * 16 + l15;
                    const int qw = qtrow + l4 * 4 + r;
                    float sv = a[r] * SC;
                    if (kb == nq && kw > (qw & 31)) sv = -1e30f;  // causal diag
                    Sb[qw][kw] = sv;
                }
            }
        }

        __syncthreads();   // B: Sb + Vt ready

        // ---- softmax (verified structure): 4 thr/row, 8 keys each ----
        if (spart) {
            float rmax = -1e30f;
            for (int k = 0; k < 32; ++k) rmax = fmaxf(rmax, Sb[q][k]);
            const float mold  = mrow_s[q];
            const float mn    = fmaxf(mold, rmax);
            const float alpha = exp2f(mold - mn);
            float ps = 0.f;
#pragma unroll
            for (int i = 0; i < 8; ++i) {
                const int k = c * 8 + i;
                const float p = exp2f(Sb[q][k] - mn);
                ps += p;
                Pb[q][k] = __builtin_bit_cast(unsigned short, (__bf16)p);
            }
            ps += __shfl_xor(ps, 1);
            ps += __shfl_xor(ps, 2);
            if (c == 0) {
                mrow_s[q]  = mn;
                alpha_s[q] = alpha;
                lrow_s[q]  = lrow_s[q] * alpha + ps;
            }
        }

        __syncthreads();   // C: Pb + stats ready

        // ---- MFMA PV (verified r5): 16 rows x 64 d per wave, 4 tiles ----
        if (part) {
            bf16x8 pf = *reinterpret_cast<const bf16x8*>(&Pb[qtrow + l15][l4 * 8]);
            float al[4];
#pragma unroll
            for (int r = 0; r < 4; ++r) al[r] = alpha_s[qtrow + l4 * 4 + r];
#pragma unroll
            for (int dt = 0; dt < 4; ++dt) {
                bf16x8 vf = *reinterpret_cast<const bf16x8*>(&Vt[dt * 16 + l15][l4 * 8]);
#pragma unroll
                for (int r = 0; r < 4; ++r) acc[dt][r] *= al[r];
                acc[dt] = __builtin_amdgcn_mfma_f32_16x16x32_bf16(pf, vf, acc[dt], 0, 0, 0);
            }
        }
    }

    // ---- epilogue (verified r5 pattern): rows qtrow + l4*4 + r ----
#pragma unroll
    for (int r = 0; r < 4; ++r) {
        const int qw = qtrow + l4 * 4 + r;
        const float inv = 1.0f / lrow_s[qw];
        float* op = O + base + (size_t)(n0 * 32 + qw) * DIM + l15;
        op[0]  = acc[0][r] * inv;
        op[16] = acc[1][r] * inv;
        op[32] = acc[2][r] * inv;
        op[48] = acc[3][r] * inv;
    }
}

extern "C" void kernel_launch(void* const* d_in, const int* in_sizes, int n_in,
                              void* d_out, int out_size, void* d_ws, size_t ws_size,
                              hipStream_t stream)
{
    const float* Q = (const float*)d_in[0];
    const float* K = (const float*)d_in[1];
    const float* V = (const float*)d_in[2];
    float*       O = (float*)d_out;

    const int nwg = 2 * NH * GROUPS;   // 512 = (b*h) x group
    hipLaunchKernelGGL(sparse_attn_grp, dim3(nwg), dim3(512), 0, stream,
                       Q, K, V, O);
}